// Round 1
// baseline (393.257 us; speedup 1.0000x reference)
//
#include <hip/hip_runtime.h>
#include <math.h>

#define H_ 1024
#define W_ 2048
#define HW_ (H_ * W_)

// Constants from the reference
#define H_STEPF   0.0029296875f            // 6/2048
#define FLUXF     0.87890625f              // 300*H_STEP  (== src == flux)
#define F_FACT    0.002574920654296875f    // src*H_STEP = 300*(6/2048)^2
#define WC0VF     65.96910698f             // 651.83*202.412*0.001/2
#define POROUS_K  0.521986224f             // C1*C2*C4*CT = 0.65248278*0.002*400*1

// b after the sequential .at[].set() chain (later writes win):
//   b[0,:]=3, b[-1,:]=3   (last)
//   b[:,-1]=3
//   b[:,1]=0
//   b[1,1:]=0, b[-2,1:]=0 (first)
__device__ __forceinline__ int compute_b(const int* __restrict__ bpl, int i, int j) {
    if (i == 0 || i == H_ - 1) return 3;
    if (j == W_ - 1) return 3;
    if (j == 1) return 0;
    if ((i == 1 || i == H_ - 2) && j >= 1) return 0;
    return bpl[i * W_ + j];
}

__global__ void init_ws(double* __restrict__ ws) {
    if (threadIdx.x < 3) ws[threadIdx.x] = 0.0;
}

// Pass 1: write heat_bc + eq_mask, reduce sum(wc_bc) into ws[0]
__global__ void k1_mask(const int* __restrict__ layout,
                        const float* __restrict__ heat,
                        const float* __restrict__ wc,
                        float* __restrict__ out_hb,
                        float* __restrict__ out_eq,
                        double* __restrict__ ws) {
    int idx = blockIdx.x * blockDim.x + threadIdx.x;
    float wacc = 0.0f;
    if (idx < HW_) {
        int i = idx >> 11;            // / 2048
        int j = idx & (W_ - 1);
        int b = compute_b(layout + HW_, i, j);   // plane 1
        float h = heat[idx];
        out_hb[idx] = (b != 1) ? h : 0.0f;
        out_eq[idx] = (b == 1) ? 0.0f : (float)b;
        if (b > 3) wacc = wc[idx];
    }
    #pragma unroll
    for (int off = 32; off > 0; off >>= 1) wacc += __shfl_down(wacc, off, 64);
    __shared__ float sred[4];
    int lane = threadIdx.x & 63, wid = threadIdx.x >> 6;
    if (lane == 0) sred[wid] = wacc;
    __syncthreads();
    if (threadIdx.x == 0)
        atomicAdd(&ws[0], (double)(sred[0] + sred[1] + sred[2] + sred[3]));
}

// Pass 2: stencil + thermo + both loss sums (ws[1]=energy, ws[2]=wc)
__global__ void k2_main(const int* __restrict__ layout,
                        const float* __restrict__ heat_ini,
                        const float* __restrict__ wc,
                        const float* __restrict__ flow,
                        const float* __restrict__ hb,
                        double* __restrict__ ws) {
    int idx = blockIdx.x * blockDim.x + threadIdx.x;
    float acc_e = 0.0f, acc_w = 0.0f;
    if (idx < HW_) {
        int i = idx >> 11;
        int j = idx & (W_ - 1);
        const int* bpl = layout + HW_;
        int b = compute_b(bpl, i, j);

        // porous (scalar, from pass-1 mean)
        float mean_wc = (float)(ws[0] * (1.0 / (double)HW_));
        float C3 = sqrtf(mean_wc / WC0VF);
        float porous = POROUS_K * C3;

        // reflect-padded central differences of heat_bc
        int jm = (j == 0) ? 1 : j - 1;
        int jp = (j == W_ - 1) ? W_ - 2 : j + 1;
        int im = (i == 0) ? 1 : i - 1;
        int ip = (i == H_ - 1) ? H_ - 2 : i + 1;
        float dx = 0.5f * (hb[i * W_ + jp] - hb[i * W_ + jm]);
        float dy = 0.5f * (hb[ip * W_ + j] - hb[im * W_ + j]);

        float u = flow[idx];
        float v = flow[HW_ + idx];
        float ad = heat_ini[idx] - 0.001f * (u * dx + v * dy);  // DIFF==0

        // _evp thermo
        float t  = hb[idx] + 273.15f;
        float t2 = t * t;
        float t3 = t2 * t;
        float cp_a = (28.11f + 0.001967f * t + 4.802e-6f * t2 - 1.966e-9f * t3)
                     / 28.97f * 1000.0f;
        float cp_v = (32.24f + 0.001923f * t + 1.055e-5f * t2 - 3.595e-9f * t3)
                     / 18.015f * 1000.0f;
        float P_v = expf(23.2f - 3816.4f / (t - 46.1f));
        float x_v = 0.62198f * P_v / (101325.0f - P_v);
        float m_dot = 300.0f / (cp_a + cp_v * 0.00725f) * (x_v - 0.00725f) * porous;
        float wcv = WC0VF - 0.001f * m_dot;

        // extras per b (cx,cy signs on flux*dx, flux*dy)
        float cx = (b == 4 || b == 9 || b == 10) ? 1.0f
                 : ((b == 6 || b == 8 || b == 11) ? -1.0f : 0.0f);
        float cy = (b == 7 || b == 8 || b == 9) ? 1.0f
                 : ((b == 5 || b == 10 || b == 11) ? -1.0f : 0.0f);
        float extra = (b >= 4) ? (FLUXF * (cx * dx + cy * dy) + wcv) : 0.0f;
        float loss_eq = (b == 1) ? 0.0f : (ad + extra);

        // f from geom (layout plane 0, rows 0/H-1 forced to 1.0 -> f=0)
        float geom = (i == 0 || i == H_ - 1) ? 1.0f : (float)layout[idx];
        float f = fabsf(geom - 1.0f) * F_FACT;

        float e = loss_eq - f;
        acc_e = e * e;

        float wmask = (b > 3) ? 1.0f : 0.0f;
        float wcb = wmask * wc[idx];
        float wterm = WC0VF * wmask - m_dot - wcb;
        acc_w = wterm * wterm;
    }
    #pragma unroll
    for (int off = 32; off > 0; off >>= 1) {
        acc_e += __shfl_down(acc_e, off, 64);
        acc_w += __shfl_down(acc_w, off, 64);
    }
    __shared__ float se[4], sw[4];
    int lane = threadIdx.x & 63, wid = threadIdx.x >> 6;
    if (lane == 0) { se[wid] = acc_e; sw[wid] = acc_w; }
    __syncthreads();
    if (threadIdx.x == 0) {
        atomicAdd(&ws[1], (double)(se[0] + se[1] + se[2] + se[3]));
        atomicAdd(&ws[2], (double)(sw[0] + sw[1] + sw[2] + sw[3]));
    }
}

__global__ void k3_final(const double* __restrict__ ws, float* __restrict__ out) {
    if (threadIdx.x == 0)
        out[0] = (float)((ws[1] + ws[2]) * (1.0 / (double)HW_));
}

extern "C" void kernel_launch(void* const* d_in, const int* in_sizes, int n_in,
                              void* d_out, int out_size, void* d_ws, size_t ws_size,
                              hipStream_t stream) {
    const int*   layout   = (const int*)d_in[0];    // (1,2,H,W) int32
    const float* heat_ini = (const float*)d_in[1];  // (1,1,H,W)
    const float* wc       = (const float*)d_in[2];  // (1,1,H,W)
    const float* heat     = (const float*)d_in[3];  // (1,1,H,W)
    const float* flow     = (const float*)d_in[4];  // (1,2,H,W)
    float*  out = (float*)d_out;                    // [loss(1), heat_bc(HW), eq_mask(HW)]
    double* ws  = (double*)d_ws;                    // [sum_wc, sum_e, sum_w]

    float* out_hb = out + 1;
    float* out_eq = out + 1 + HW_;

    init_ws<<<1, 64, 0, stream>>>(ws);
    k1_mask<<<HW_ / 256, 256, 0, stream>>>(layout, heat, wc, out_hb, out_eq, ws);
    k2_main<<<HW_ / 256, 256, 0, stream>>>(layout, heat_ini, wc, flow, out_hb, ws);
    k3_final<<<1, 1, 0, stream>>>(ws, out);
}

// Round 2
// 181.442 us; speedup vs baseline: 2.1674x; 2.1674x over previous
//
#include <hip/hip_runtime.h>
#include <math.h>

#define H_ 1024
#define W_ 2048
#define HW_ (H_ * W_)

#define FLUXF     0.87890625f              // 300*(6/2048)
#define F_FACT    0.002574920654296875f    // 300*(6/2048)^2
#define WC0VF     65.96910698f             // 651.83*202.412*0.001/2
#define POROUS_K  0.521986224f             // C1*C2*C4*CT

// b after the sequential .at[].set() chain (later writes win):
//   b[0,:]=3, b[-1,:]=3 ; b[:,-1]=3 ; b[:,1]=0 ; b[1,1:]=0, b[-2,1:]=0
__device__ __forceinline__ int fix_b(int raw, int i, int j) {
    if (i == 0 || i == H_ - 1) return 3;
    if (j == W_ - 1) return 3;
    if (j == 1) return 0;
    if (i == 1 || i == H_ - 2) return 0;
    return raw;
}

__global__ void init_ws(float* __restrict__ ws) {
    if (threadIdx.x < 3) ws[threadIdx.x] = 0.0f;
}

// Pass 1: heat_bc + eq_mask out, reduce sum(wc_bc) -> ws[0]. 4 elems/thread.
__global__ void k1_mask(const int* __restrict__ layout,
                        const float* __restrict__ heat,
                        const float* __restrict__ wc,
                        float* __restrict__ out_hb,
                        float* __restrict__ out_eq,
                        float* __restrict__ ws) {
    int gid  = blockIdx.x * blockDim.x + threadIdx.x;   // 0 .. HW/4-1
    int idx4 = gid << 2;
    int i  = idx4 >> 11;
    int jb = idx4 & (W_ - 1);

    int4   b4 = *(const int4*)(layout + HW_ + idx4);
    float4 h4 = *(const float4*)(heat + idx4);
    float4 w4 = *(const float4*)(wc + idx4);

    int   bs[4] = {b4.x, b4.y, b4.z, b4.w};
    float hs[4] = {h4.x, h4.y, h4.z, h4.w};
    float wsv[4] = {w4.x, w4.y, w4.z, w4.w};
    float4 ohb, oeq;
    float* ph = &ohb.x; float* pe = &oeq.x;
    float wacc = 0.0f;
    #pragma unroll
    for (int k = 0; k < 4; k++) {
        int b = fix_b(bs[k], i, jb + k);
        ph[k] = (b != 1) ? hs[k] : 0.0f;
        pe[k] = (b == 1) ? 0.0f : (float)b;
        if (b > 3) wacc += wsv[k];
    }
    *(float4*)(out_hb + idx4) = ohb;
    *(float4*)(out_eq + idx4) = oeq;

    #pragma unroll
    for (int off = 32; off > 0; off >>= 1) wacc += __shfl_down(wacc, off, 64);
    __shared__ float sred[4];
    int lane = threadIdx.x & 63, wid = threadIdx.x >> 6;
    if (lane == 0) sred[wid] = wacc;
    __syncthreads();
    if (threadIdx.x == 0)
        atomicAdd(&ws[0], sred[0] + sred[1] + sred[2] + sred[3]);
}

// Pass 2: stencil + thermo + both loss sums. 4 elems/thread.
__global__ void k2_main(const int* __restrict__ layout,
                        const float* __restrict__ heat_ini,
                        const float* __restrict__ wc,
                        const float* __restrict__ flow,
                        const float* __restrict__ hb,
                        float* __restrict__ ws) {
    int gid  = blockIdx.x * blockDim.x + threadIdx.x;
    int idx4 = gid << 2;
    int i  = idx4 >> 11;
    int jb = idx4 & (W_ - 1);
    int im = (i == 0) ? 1 : i - 1;
    int ip = (i == H_ - 1) ? H_ - 2 : i + 1;

    float mean_wc = ws[0] * (1.0f / (float)HW_);
    float porous  = POROUS_K * sqrtf(mean_wc / WC0VF);

    float4 hc = *(const float4*)(hb + i * W_ + jb);
    float4 hu = *(const float4*)(hb + im * W_ + jb);
    float4 hd = *(const float4*)(hb + ip * W_ + jb);
    float  hl = (jb == 0) ? 0.0f : hb[i * W_ + jb - 1];
    float  hr = (jb == W_ - 4) ? 0.0f : hb[i * W_ + jb + 4];

    int4   b4  = *(const int4*)(layout + HW_ + idx4);
    int4   g4  = *(const int4*)(layout + idx4);
    float4 hi4 = *(const float4*)(heat_ini + idx4);
    float4 w4  = *(const float4*)(wc + idx4);
    float4 u4  = *(const float4*)(flow + idx4);
    float4 v4  = *(const float4*)(flow + HW_ + idx4);

    float dxs[4];
    dxs[0] = (jb == 0) ? 0.0f : 0.5f * (hc.y - hl);
    dxs[1] = 0.5f * (hc.z - hc.x);
    dxs[2] = 0.5f * (hc.w - hc.y);
    dxs[3] = (jb == W_ - 4) ? 0.0f : 0.5f * (hr - hc.z);

    const float* phc = &hc.x; const float* phu = &hu.x; const float* phd = &hd.x;
    int   bs[4] = {b4.x, b4.y, b4.z, b4.w};
    int   gs[4] = {g4.x, g4.y, g4.z, g4.w};
    float his[4] = {hi4.x, hi4.y, hi4.z, hi4.w};
    float wss[4] = {w4.x, w4.y, w4.z, w4.w};
    float us[4] = {u4.x, u4.y, u4.z, u4.w};
    float vs[4] = {v4.x, v4.y, v4.z, v4.w};

    float acc_e = 0.0f, acc_w = 0.0f;
    #pragma unroll
    for (int k = 0; k < 4; k++) {
        int j = jb + k;
        int b = fix_b(bs[k], i, j);
        float dx = dxs[k];
        float dy = 0.5f * (phd[k] - phu[k]);      // exactly 0 at i=0 / i=H-1

        float ad = his[k] - 0.001f * (us[k] * dx + vs[k] * dy);

        float t  = phc[k] + 273.15f;
        float t2 = t * t, t3 = t2 * t;
        float cp_a = (28.11f + 0.001967f * t + 4.802e-6f * t2 - 1.966e-9f * t3)
                     * (1000.0f / 28.97f);
        float cp_v = (32.24f + 0.001923f * t + 1.055e-5f * t2 - 3.595e-9f * t3)
                     * (1000.0f / 18.015f);
        float P_v = expf(23.2f - 3816.4f / (t - 46.1f));
        float x_v = 0.62198f * P_v / (101325.0f - P_v);
        float m_dot = 300.0f / (cp_a + cp_v * 0.00725f) * (x_v - 0.00725f) * porous;
        float wcv = WC0VF - 0.001f * m_dot;

        float cx = (b == 4 || b == 9 || b == 10) ? 1.0f
                 : ((b == 6 || b == 8 || b == 11) ? -1.0f : 0.0f);
        float cy = (b == 7 || b == 8 || b == 9) ? 1.0f
                 : ((b == 5 || b == 10 || b == 11) ? -1.0f : 0.0f);
        float extra = (b >= 4) ? (FLUXF * (cx * dx + cy * dy) + wcv) : 0.0f;
        float loss_eq = (b == 1) ? 0.0f : (ad + extra);

        float geom = (i == 0 || i == H_ - 1) ? 1.0f : (float)gs[k];
        float e = loss_eq - fabsf(geom - 1.0f) * F_FACT;
        acc_e += e * e;

        float wmask = (b > 3) ? 1.0f : 0.0f;
        float wterm = WC0VF * wmask - m_dot - wmask * wss[k];
        acc_w += wterm * wterm;
    }

    #pragma unroll
    for (int off = 32; off > 0; off >>= 1) {
        acc_e += __shfl_down(acc_e, off, 64);
        acc_w += __shfl_down(acc_w, off, 64);
    }
    __shared__ float se[4], sw[4];
    int lane = threadIdx.x & 63, wid = threadIdx.x >> 6;
    if (lane == 0) { se[wid] = acc_e; sw[wid] = acc_w; }
    __syncthreads();
    if (threadIdx.x == 0) {
        atomicAdd(&ws[1], se[0] + se[1] + se[2] + se[3]);
        atomicAdd(&ws[2], sw[0] + sw[1] + sw[2] + sw[3]);
    }
}

__global__ void k3_final(const float* __restrict__ ws, float* __restrict__ out) {
    if (threadIdx.x == 0)
        out[0] = (ws[1] + ws[2]) * (1.0f / (float)HW_);
}

extern "C" void kernel_launch(void* const* d_in, const int* in_sizes, int n_in,
                              void* d_out, int out_size, void* d_ws, size_t ws_size,
                              hipStream_t stream) {
    const int*   layout   = (const int*)d_in[0];
    const float* heat_ini = (const float*)d_in[1];
    const float* wc       = (const float*)d_in[2];
    const float* heat     = (const float*)d_in[3];
    const float* flow     = (const float*)d_in[4];
    float* out = (float*)d_out;    // [loss(1), heat_bc(HW), eq_mask(HW)]
    float* ws  = (float*)d_ws;     // [sum_wc, sum_e, sum_w]

    float* out_hb = out + 1;
    float* out_eq = out + 1 + HW_;

    init_ws<<<1, 64, 0, stream>>>(ws);
    k1_mask<<<HW_ / (256 * 4), 256, 0, stream>>>(layout, heat, wc, out_hb, out_eq, ws);
    k2_main<<<HW_ / (256 * 4), 256, 0, stream>>>(layout, heat_ini, wc, flow, out_hb, ws);
    k3_final<<<1, 1, 0, stream>>>(ws, out);
}

// Round 3
// 127.073 us; speedup vs baseline: 3.0947x; 1.4279x over previous
//
#include <hip/hip_runtime.h>
#include <math.h>

#define H_ 1024
#define W_ 2048
#define HW_ (H_ * W_)
#define NB_ 2048                           // main-kernel block count

#define FLUXF     0.87890625f              // 300*(6/2048)
#define F_FACT    0.002574920654296875f    // 300*(6/2048)^2
#define WC0VF     65.96910698f             // 651.83*202.412*0.001/2
#define POROUS_K  0.521986224f             // C1*C2*C4*CT

// b after the sequential .at[].set() chain (later writes win):
//   b[0,:]=3, b[-1,:]=3 ; b[:,-1]=3 ; b[:,1]=0 ; b[1,1:]=0, b[-2,1:]=0
// NOTE the j>=1 guard: b[1,0] / b[H-2,0] keep their raw value.
__device__ __forceinline__ int fix_b(int raw, int i, int j) {
    if (i == 0 || i == H_ - 1) return 3;
    if (j == W_ - 1) return 3;
    if (j == 1) return 0;
    if ((i == 1 || i == H_ - 2) && j >= 1) return 0;
    return raw;
}

// One pass: write heat_bc + eq_mask; accumulate 7 moments per block:
//  s0=sum(wc_bc)  s1=sum(a^2)  s2=sum(a*c)  s3=sum(c^2)
//  s4=sum(aw^2)   s5=sum(aw*q) s6=sum(q^2)
// where energy term e = a + p*c, wc term w = aw - p*q, p = porous (scalar).
__global__ __launch_bounds__(256)
void k_main(const int* __restrict__ layout, const float* __restrict__ heat_ini,
            const float* __restrict__ wc, const float* __restrict__ heat,
            const float* __restrict__ flow, float* __restrict__ out_hb,
            float* __restrict__ out_eq, float* __restrict__ ws) {
    int gid  = blockIdx.x * 256 + threadIdx.x;
    int idx4 = gid << 2;
    int i  = idx4 >> 11;
    int jb = idx4 & (W_ - 1);
    int im = (i == 0) ? 1 : i - 1;
    int ip = (i == H_ - 1) ? H_ - 2 : i + 1;
    const int* L1 = layout + HW_;

    int4   bc4 = *(const int4*)(L1 + idx4);
    int4   bu4 = *(const int4*)(L1 + im * W_ + jb);
    int4   bd4 = *(const int4*)(L1 + ip * W_ + jb);
    int4   g4  = *(const int4*)(layout + idx4);
    float4 hc4 = *(const float4*)(heat + idx4);
    float4 hu4 = *(const float4*)(heat + im * W_ + jb);
    float4 hd4 = *(const float4*)(heat + ip * W_ + jb);
    float4 hi4 = *(const float4*)(heat_ini + idx4);
    float4 w4  = *(const float4*)(wc + idx4);
    float4 u4  = *(const float4*)(flow + idx4);
    float4 v4  = *(const float4*)(flow + HW_ + idx4);

    float hl = 0.0f, hr = 0.0f; int bl = 0, br = 0;
    if (jb != 0)      { hl = heat[idx4 - 1]; bl = L1[idx4 - 1]; }
    if (jb != W_ - 4) { hr = heat[idx4 + 4]; br = L1[idx4 + 4]; }

    int   bcs[4] = {bc4.x, bc4.y, bc4.z, bc4.w};
    int   bus[4] = {bu4.x, bu4.y, bu4.z, bu4.w};
    int   bds[4] = {bd4.x, bd4.y, bd4.z, bd4.w};
    int   gs[4]  = {g4.x, g4.y, g4.z, g4.w};
    float hcs[4] = {hc4.x, hc4.y, hc4.z, hc4.w};
    float hus[4] = {hu4.x, hu4.y, hu4.z, hu4.w};
    float hds[4] = {hd4.x, hd4.y, hd4.z, hd4.w};
    float his[4] = {hi4.x, hi4.y, hi4.z, hi4.w};
    float wss[4] = {w4.x, w4.y, w4.z, w4.w};
    float us[4]  = {u4.x, u4.y, u4.z, u4.w};
    float vs[4]  = {v4.x, v4.y, v4.z, v4.w};

    // masked heat_bc values: 6 center-row (incl. halo), 4 up, 4 down
    int bfix[4];
    float hb6[6];
    hb6[0] = (fix_b(bl, i, jb - 1) != 1) ? hl : 0.0f;
    hb6[5] = (fix_b(br, i, jb + 4) != 1) ? hr : 0.0f;
    float4 ohb, oeq;
    float* pohb = &ohb.x; float* poeq = &oeq.x;
    #pragma unroll
    for (int k = 0; k < 4; k++) {
        int b = fix_b(bcs[k], i, jb + k);
        bfix[k] = b;
        float hbv = (b != 1) ? hcs[k] : 0.0f;
        hb6[k + 1] = hbv;
        pohb[k] = hbv;
        poeq[k] = (b == 1) ? 0.0f : (float)b;
    }
    *(float4*)(out_hb + idx4) = ohb;
    *(float4*)(out_eq + idx4) = oeq;

    float acc[7] = {0.f, 0.f, 0.f, 0.f, 0.f, 0.f, 0.f};
    #pragma unroll
    for (int k = 0; k < 4; k++) {
        int j = jb + k;
        int b = bfix[k];
        float dx = 0.5f * (hb6[k + 2] - hb6[k]);
        if (j == 0 || j == W_ - 1) dx = 0.0f;              // reflect edges
        float hbu = (fix_b(bus[k], im, j) != 1) ? hus[k] : 0.0f;
        float hbd = (fix_b(bds[k], ip, j) != 1) ? hds[k] : 0.0f;
        float dy = 0.5f * (hbd - hbu);                     // auto-0 at i=0/H-1

        float ad = his[k] - 0.001f * (us[k] * dx + vs[k] * dy);

        // q(t): m_dot = porous * q
        float t  = hb6[k + 1] + 273.15f;
        float t2 = t * t, t3 = t2 * t;
        float cp_a = (28.11f + 0.001967f * t + 4.802e-6f * t2 - 1.966e-9f * t3)
                     * (1000.0f / 28.97f);
        float cp_v = (32.24f + 0.001923f * t + 1.055e-5f * t2 - 3.595e-9f * t3)
                     * (1000.0f / 18.015f);
        float P_v = expf(23.2f - 3816.4f / (t - 46.1f));
        float x_v = 0.62198f * P_v / (101325.0f - P_v);
        float q = 300.0f / (cp_a + cp_v * 0.00725f) * (x_v - 0.00725f);

        float f = (i == 0 || i == H_ - 1) ? 0.0f
                  : fabsf((float)gs[k] - 1.0f) * F_FACT;

        float a_e, c_e;
        if (b == 1) {
            a_e = -f; c_e = 0.0f;
        } else {
            float cx = (b == 4 || b == 9 || b == 10) ? 1.0f
                     : ((b == 6 || b == 8 || b == 11) ? -1.0f : 0.0f);
            float cy = (b == 7 || b == 8 || b == 9) ? 1.0f
                     : ((b == 5 || b == 10 || b == 11) ? -1.0f : 0.0f);
            float extra0 = (b >= 4) ? (FLUXF * (cx * dx + cy * dy) + WC0VF) : 0.0f;
            a_e = ad + extra0 - f;
            c_e = (b >= 4) ? (-0.001f * q) : 0.0f;
        }
        acc[1] += a_e * a_e;
        acc[2] += a_e * c_e;
        acc[3] += c_e * c_e;

        float wm  = (b > 3) ? 1.0f : 0.0f;
        float wcb = wm * wss[k];
        float aw  = WC0VF * wm - wcb;
        acc[0] += wcb;
        acc[4] += aw * aw;
        acc[5] += aw * q;
        acc[6] += q * q;
    }

    #pragma unroll
    for (int off = 32; off > 0; off >>= 1) {
        #pragma unroll
        for (int s = 0; s < 7; s++) acc[s] += __shfl_down(acc[s], off, 64);
    }
    __shared__ float red[4][7];
    int lane = threadIdx.x & 63, wid = threadIdx.x >> 6;
    if (lane == 0) {
        #pragma unroll
        for (int s = 0; s < 7; s++) red[wid][s] = acc[s];
    }
    __syncthreads();
    if (threadIdx.x == 0) {
        #pragma unroll
        for (int s = 0; s < 7; s++)
            ws[s * NB_ + blockIdx.x] =
                red[0][s] + red[1][s] + red[2][s] + red[3][s];
    }
}

// Reduce 2048 partials per moment, compute porous, evaluate quadratics.
__global__ __launch_bounds__(256)
void k_final(const float* __restrict__ ws, float* __restrict__ out) {
    __shared__ float sred[7][4];
    int tid = threadIdx.x;
    #pragma unroll
    for (int s = 0; s < 7; s++) {
        float a = 0.0f;
        for (int t = tid; t < NB_; t += 256) a += ws[s * NB_ + t];
        #pragma unroll
        for (int off = 32; off > 0; off >>= 1) a += __shfl_down(a, off, 64);
        if ((tid & 63) == 0) sred[s][tid >> 6] = a;
    }
    __syncthreads();
    if (tid == 0) {
        float S[7];
        #pragma unroll
        for (int s = 0; s < 7; s++)
            S[s] = sred[s][0] + sred[s][1] + sred[s][2] + sred[s][3];
        float mean_wc = S[0] * (1.0f / (float)HW_);
        float p = POROUS_K * sqrtf(mean_wc / WC0VF);
        float energy = S[1] + 2.0f * p * S[2] + p * p * S[3];
        float wcl    = S[4] - 2.0f * p * S[5] + p * p * S[6];
        out[0] = (energy + wcl) * (1.0f / (float)HW_);
    }
}

extern "C" void kernel_launch(void* const* d_in, const int* in_sizes, int n_in,
                              void* d_out, int out_size, void* d_ws, size_t ws_size,
                              hipStream_t stream) {
    const int*   layout   = (const int*)d_in[0];
    const float* heat_ini = (const float*)d_in[1];
    const float* wc       = (const float*)d_in[2];
    const float* heat     = (const float*)d_in[3];
    const float* flow     = (const float*)d_in[4];
    float* out = (float*)d_out;    // [loss(1), heat_bc(HW), eq_mask(HW)]
    float* ws  = (float*)d_ws;     // 7 * NB_ block partials (SoA)

    float* out_hb = out + 1;
    float* out_eq = out + 1 + HW_;

    k_main<<<NB_, 256, 0, stream>>>(layout, heat_ini, wc, heat, flow,
                                    out_hb, out_eq, ws);
    k_final<<<1, 256, 0, stream>>>(ws, out);
}

// Round 4
// 114.689 us; speedup vs baseline: 3.4289x; 1.1080x over previous
//
#include <hip/hip_runtime.h>
#include <math.h>

#define H_ 1024
#define W_ 2048
#define HW_ (H_ * W_)
#define NB_ 1024                           // one block per row

#define FLUXF     0.87890625f              // 300*(6/2048)
#define F_FACT    0.002574920654296875f    // 300*(6/2048)^2
#define WC0VF     65.96910698f             // 651.83*202.412*0.001/2
#define POROUS_K  0.521986224f             // C1*C2*C4*CT

// b after the sequential .at[].set() chain (later writes win):
//   b[0,:]=3, b[-1,:]=3 ; b[:,-1]=3 ; b[:,1]=0 ; b[1,1:]=0, b[-2,1:]=0 (j>=1!)
__device__ __forceinline__ int fix_b(int raw, int i, int j) {
    if (i == 0 || i == H_ - 1) return 3;
    if (j == W_ - 1) return 3;
    if (j == 1) return 0;
    if ((i == 1 || i == H_ - 2) && j >= 1) return 0;
    return raw;
}

// One row per block, 8 px/thread. Moments (quadratic-in-porous split):
//  s0=sum(wc_bc) s1=sum(a^2) s2=sum(a*c) s3=sum(c^2)
//  s4=sum(aw^2)  s5=sum(aw*q) s6=sum(q^2);  e=a+p*c, w=aw-p*q.
__global__ __launch_bounds__(256)
void k_main(const int* __restrict__ layout, const float* __restrict__ heat_ini,
            const float* __restrict__ wc, const float* __restrict__ heat,
            const float* __restrict__ flow, float* __restrict__ out_hb,
            float* __restrict__ out_eq, float* __restrict__ ws) {
    const int i  = blockIdx.x;
    const int jb = threadIdx.x << 3;
    const int im = (i == 0) ? 1 : i - 1;
    const int ip = (i == H_ - 1) ? H_ - 2 : i + 1;
    const int* L1 = layout + HW_;
    const int base  = i * W_ + jb;
    const int baseu = im * W_ + jb;
    const int based = ip * W_ + jb;

    int4   bc0 = *(const int4*)(L1 + base),      bc1 = *(const int4*)(L1 + base + 4);
    int4   bu0 = *(const int4*)(L1 + baseu),     bu1 = *(const int4*)(L1 + baseu + 4);
    int4   bd0 = *(const int4*)(L1 + based),     bd1 = *(const int4*)(L1 + based + 4);
    int4   g0  = *(const int4*)(layout + base),  g1  = *(const int4*)(layout + base + 4);
    float4 hc0 = *(const float4*)(heat + base),  hc1 = *(const float4*)(heat + base + 4);
    float4 hu0 = *(const float4*)(heat + baseu), hu1 = *(const float4*)(heat + baseu + 4);
    float4 hd0 = *(const float4*)(heat + based), hd1 = *(const float4*)(heat + based + 4);
    float4 hi0 = *(const float4*)(heat_ini + base), hi1 = *(const float4*)(heat_ini + base + 4);
    float4 w0  = *(const float4*)(wc + base),    w1  = *(const float4*)(wc + base + 4);
    float4 u0  = *(const float4*)(flow + base),  u1  = *(const float4*)(flow + base + 4);
    float4 v0  = *(const float4*)(flow + HW_ + base), v1 = *(const float4*)(flow + HW_ + base + 4);

    int   bcs[8] = {bc0.x,bc0.y,bc0.z,bc0.w, bc1.x,bc1.y,bc1.z,bc1.w};
    int   bus[8] = {bu0.x,bu0.y,bu0.z,bu0.w, bu1.x,bu1.y,bu1.z,bu1.w};
    int   bds[8] = {bd0.x,bd0.y,bd0.z,bd0.w, bd1.x,bd1.y,bd1.z,bd1.w};
    int   gs[8]  = {g0.x,g0.y,g0.z,g0.w, g1.x,g1.y,g1.z,g1.w};
    float hcs[8] = {hc0.x,hc0.y,hc0.z,hc0.w, hc1.x,hc1.y,hc1.z,hc1.w};
    float hus[8] = {hu0.x,hu0.y,hu0.z,hu0.w, hu1.x,hu1.y,hu1.z,hu1.w};
    float hds[8] = {hd0.x,hd0.y,hd0.z,hd0.w, hd1.x,hd1.y,hd1.z,hd1.w};
    float his[8] = {hi0.x,hi0.y,hi0.z,hi0.w, hi1.x,hi1.y,hi1.z,hi1.w};
    float wss[8] = {w0.x,w0.y,w0.z,w0.w, w1.x,w1.y,w1.z,w1.w};
    float us[8]  = {u0.x,u0.y,u0.z,u0.w, u1.x,u1.y,u1.z,u1.w};
    float vs[8]  = {v0.x,v0.y,v0.z,v0.w, v1.x,v1.y,v1.z,v1.w};

    __shared__ float shb[W_];
    int   bfix[8];
    float hb8[8], oeqs[8];
    #pragma unroll
    for (int k = 0; k < 8; k++) {
        int b = fix_b(bcs[k], i, jb + k);
        bfix[k] = b;
        hb8[k]  = (b != 1) ? hcs[k] : 0.0f;
        oeqs[k] = (b == 1) ? 0.0f : (float)b;
    }
    *(float4*)(shb + jb)     = make_float4(hb8[0], hb8[1], hb8[2], hb8[3]);
    *(float4*)(shb + jb + 4) = make_float4(hb8[4], hb8[5], hb8[6], hb8[7]);
    *(float4*)(out_hb + base)     = make_float4(hb8[0], hb8[1], hb8[2], hb8[3]);
    *(float4*)(out_hb + base + 4) = make_float4(hb8[4], hb8[5], hb8[6], hb8[7]);
    *(float4*)(out_eq + base)     = make_float4(oeqs[0], oeqs[1], oeqs[2], oeqs[3]);
    *(float4*)(out_eq + base + 4) = make_float4(oeqs[4], oeqs[5], oeqs[6], oeqs[7]);
    __syncthreads();

    float acc[7] = {0.f,0.f,0.f,0.f,0.f,0.f,0.f};
    #pragma unroll
    for (int k = 0; k < 8; k++) {
        int j = jb + k;
        int b = bfix[k];
        float hl = (k == 0) ? ((j == 0) ? 0.0f : shb[j - 1]) : hb8[k - 1];
        float hr = (k == 7) ? ((j == W_ - 1) ? 0.0f : shb[j + 1]) : hb8[k + 1];
        float dx = (j == 0 || j == W_ - 1) ? 0.0f : 0.5f * (hr - hl);
        float hbu = (fix_b(bus[k], im, j) != 1) ? hus[k] : 0.0f;
        float hbd = (fix_b(bds[k], ip, j) != 1) ? hds[k] : 0.0f;
        float dy = 0.5f * (hbd - hbu);                  // auto-0 at i=0/H-1

        float ad = his[k] - 0.001f * (us[k] * dx + vs[k] * dy);

        float t  = hb8[k] + 273.15f;
        float t2 = t * t, t3 = t2 * t;
        float cp_a = (28.11f + 0.001967f * t + 4.802e-6f * t2 - 1.966e-9f * t3)
                     * (1000.0f / 28.97f);
        float cp_v = (32.24f + 0.001923f * t + 1.055e-5f * t2 - 3.595e-9f * t3)
                     * (1000.0f / 18.015f);
        float P_v = expf(23.2f - 3816.4f / (t - 46.1f));
        float x_v = 0.62198f * P_v / (101325.0f - P_v);
        float q = 300.0f / (cp_a + cp_v * 0.00725f) * (x_v - 0.00725f);

        float f = (i == 0 || i == H_ - 1) ? 0.0f
                  : fabsf((float)gs[k] - 1.0f) * F_FACT;

        float a_e, c_e;
        if (b == 1) {
            a_e = -f; c_e = 0.0f;
        } else {
            float cx = (b == 4 || b == 9 || b == 10) ? 1.0f
                     : ((b == 6 || b == 8 || b == 11) ? -1.0f : 0.0f);
            float cy = (b == 7 || b == 8 || b == 9) ? 1.0f
                     : ((b == 5 || b == 10 || b == 11) ? -1.0f : 0.0f);
            float extra0 = (b >= 4) ? (FLUXF * (cx * dx + cy * dy) + WC0VF) : 0.0f;
            a_e = ad + extra0 - f;
            c_e = (b >= 4) ? (-0.001f * q) : 0.0f;
        }
        acc[1] += a_e * a_e;
        acc[2] += a_e * c_e;
        acc[3] += c_e * c_e;

        float wm  = (b > 3) ? 1.0f : 0.0f;
        float wcb = wm * wss[k];
        float aw  = WC0VF * wm - wcb;
        acc[0] += wcb;
        acc[4] += aw * aw;
        acc[5] += aw * q;
        acc[6] += q * q;
    }

    #pragma unroll
    for (int off = 32; off > 0; off >>= 1) {
        #pragma unroll
        for (int s = 0; s < 7; s++) acc[s] += __shfl_down(acc[s], off, 64);
    }
    __shared__ float red[4][7];
    int lane = threadIdx.x & 63, wid = threadIdx.x >> 6;
    if (lane == 0) {
        #pragma unroll
        for (int s = 0; s < 7; s++) red[wid][s] = acc[s];
    }
    __syncthreads();
    if (threadIdx.x == 0) {
        #pragma unroll
        for (int s = 0; s < 7; s++)
            ws[s * NB_ + blockIdx.x] =
                red[0][s] + red[1][s] + red[2][s] + red[3][s];
    }
}

// Reduce NB_ partials per moment (float4 reads), finish the quadratics.
__global__ __launch_bounds__(256)
void k_final(const float* __restrict__ ws, float* __restrict__ out) {
    __shared__ float sred[7][4];
    int tid = threadIdx.x;
    #pragma unroll
    for (int s = 0; s < 7; s++) {
        float4 x = *(const float4*)(ws + s * NB_ + (tid << 2));
        float a = x.x + x.y + x.z + x.w;
        #pragma unroll
        for (int off = 32; off > 0; off >>= 1) a += __shfl_down(a, off, 64);
        if ((tid & 63) == 0) sred[s][tid >> 6] = a;
    }
    __syncthreads();
    if (tid == 0) {
        float S[7];
        #pragma unroll
        for (int s = 0; s < 7; s++)
            S[s] = sred[s][0] + sred[s][1] + sred[s][2] + sred[s][3];
        float mean_wc = S[0] * (1.0f / (float)HW_);
        float p = POROUS_K * sqrtf(mean_wc / WC0VF);
        float energy = S[1] + 2.0f * p * S[2] + p * p * S[3];
        float wcl    = S[4] - 2.0f * p * S[5] + p * p * S[6];
        out[0] = (energy + wcl) * (1.0f / (float)HW_);
    }
}

extern "C" void kernel_launch(void* const* d_in, const int* in_sizes, int n_in,
                              void* d_out, int out_size, void* d_ws, size_t ws_size,
                              hipStream_t stream) {
    const int*   layout   = (const int*)d_in[0];
    const float* heat_ini = (const float*)d_in[1];
    const float* wc       = (const float*)d_in[2];
    const float* heat     = (const float*)d_in[3];
    const float* flow     = (const float*)d_in[4];
    float* out = (float*)d_out;    // [loss(1), heat_bc(HW), eq_mask(HW)]
    float* ws  = (float*)d_ws;     // 7 * NB_ block partials (SoA)

    float* out_hb = out + 1;
    float* out_eq = out + 1 + HW_;

    k_main<<<NB_, 256, 0, stream>>>(layout, heat_ini, wc, heat, flow,
                                    out_hb, out_eq, ws);
    k_final<<<1, 256, 0, stream>>>(ws, out);
}

// Round 5
// 111.367 us; speedup vs baseline: 3.5312x; 1.0298x over previous
//
#include <hip/hip_runtime.h>
#include <math.h>

#define H_ 1024
#define W_ 2048
#define HW_ (H_ * W_)
#define NB_ 2048                           // half-row per block
#define TPB_ 128
#define HALF_ 1024

#define FLUXF     0.87890625f              // 300*(6/2048)
#define F_FACT    0.002574920654296875f    // 300*(6/2048)^2
#define WC0VF     65.96910698f             // 651.83*202.412*0.001/2
#define POROUS_K  0.521986224f             // C1*C2*C4*CT

// b after the sequential .at[].set() chain (later writes win):
//   b[0,:]=3, b[-1,:]=3 ; b[:,-1]=3 ; b[:,1]=0 ; b[1,1:]=0, b[-2,1:]=0 (j>=1!)
__device__ __forceinline__ int fix_b(int raw, int i, int j) {
    if (i == 0 || i == H_ - 1) return 3;
    if (j == W_ - 1) return 3;
    if (j == 1) return 0;
    if ((i == 1 || i == H_ - 2) && j >= 1) return 0;
    return raw;
}

// Half-row per block, 8 px/thread. Moments (quadratic-in-porous split):
//  s0=sum(wc_bc) s1=sum(a^2) s2=sum(a*c) s3=sum(c^2)
//  s4=sum(aw^2)  s5=sum(aw*q) s6=sum(q^2);  e=a+p*c, w=aw-p*q.
__global__ __launch_bounds__(TPB_)
void k_main(const int* __restrict__ layout, const float* __restrict__ heat_ini,
            const float* __restrict__ wc, const float* __restrict__ heat,
            const float* __restrict__ flow, float* __restrict__ out_hb,
            float* __restrict__ out_eq, float* __restrict__ ws) {
    // XCD-strip swizzle: XCD x owns rows [x*128, (x+1)*128) -> up/down row
    // re-reads hit that XCD's own L2 instead of bouncing to L3.
    const int virt = ((blockIdx.x & 7) << 8) | (blockIdx.x >> 3);
    const int i    = virt >> 1;
    const int jb0  = (virt & 1) * HALF_;
    const int tid  = threadIdx.x;
    const int lj   = tid << 3;
    const int jb   = jb0 + lj;
    const int im = (i == 0) ? 1 : i - 1;
    const int ip = (i == H_ - 1) ? H_ - 2 : i + 1;
    const int* L1 = layout + HW_;
    const int base  = i * W_ + jb;
    const int baseu = im * W_ + jb;
    const int based = ip * W_ + jb;

    int4   bc0 = *(const int4*)(L1 + base),      bc1 = *(const int4*)(L1 + base + 4);
    int4   bu0 = *(const int4*)(L1 + baseu),     bu1 = *(const int4*)(L1 + baseu + 4);
    int4   bd0 = *(const int4*)(L1 + based),     bd1 = *(const int4*)(L1 + based + 4);
    int4   g0  = *(const int4*)(layout + base),  g1  = *(const int4*)(layout + base + 4);
    float4 hc0 = *(const float4*)(heat + base),  hc1 = *(const float4*)(heat + base + 4);
    float4 hu0 = *(const float4*)(heat + baseu), hu1 = *(const float4*)(heat + baseu + 4);
    float4 hd0 = *(const float4*)(heat + based), hd1 = *(const float4*)(heat + based + 4);
    float4 hi0 = *(const float4*)(heat_ini + base), hi1 = *(const float4*)(heat_ini + base + 4);
    float4 w0  = *(const float4*)(wc + base),    w1  = *(const float4*)(wc + base + 4);
    float4 u0  = *(const float4*)(flow + base),  u1  = *(const float4*)(flow + base + 4);
    float4 v0  = *(const float4*)(flow + HW_ + base), v1 = *(const float4*)(flow + HW_ + base + 4);

    // Block-edge halo (masked heat_bc just outside this half-row)
    __shared__ float shb[HALF_ + 2];       // shb[x+1] = masked local x
    if (tid == 0) {
        float hv = 0.0f;
        if (jb0 != 0) {
            int j = jb0 - 1;
            hv = (fix_b(L1[i * W_ + j], i, j) != 1) ? heat[i * W_ + j] : 0.0f;
        }
        shb[0] = hv;
    }
    if (tid == TPB_ - 1) {
        float hv = 0.0f;
        if (jb0 + HALF_ < W_) {
            int j = jb0 + HALF_;
            hv = (fix_b(L1[i * W_ + j], i, j) != 1) ? heat[i * W_ + j] : 0.0f;
        }
        shb[HALF_ + 1] = hv;
    }

    int   bcs[8] = {bc0.x,bc0.y,bc0.z,bc0.w, bc1.x,bc1.y,bc1.z,bc1.w};
    int   bus[8] = {bu0.x,bu0.y,bu0.z,bu0.w, bu1.x,bu1.y,bu1.z,bu1.w};
    int   bds[8] = {bd0.x,bd0.y,bd0.z,bd0.w, bd1.x,bd1.y,bd1.z,bd1.w};
    int   gs[8]  = {g0.x,g0.y,g0.z,g0.w, g1.x,g1.y,g1.z,g1.w};
    float hcs[8] = {hc0.x,hc0.y,hc0.z,hc0.w, hc1.x,hc1.y,hc1.z,hc1.w};
    float hus[8] = {hu0.x,hu0.y,hu0.z,hu0.w, hu1.x,hu1.y,hu1.z,hu1.w};
    float hds[8] = {hd0.x,hd0.y,hd0.z,hd0.w, hd1.x,hd1.y,hd1.z,hd1.w};
    float his[8] = {hi0.x,hi0.y,hi0.z,hi0.w, hi1.x,hi1.y,hi1.z,hi1.w};
    float wss[8] = {w0.x,w0.y,w0.z,w0.w, w1.x,w1.y,w1.z,w1.w};
    float us[8]  = {u0.x,u0.y,u0.z,u0.w, u1.x,u1.y,u1.z,u1.w};
    float vs[8]  = {v0.x,v0.y,v0.z,v0.w, v1.x,v1.y,v1.z,v1.w};

    int   bfix[8];
    float hb8[8], oeqs[8];
    #pragma unroll
    for (int k = 0; k < 8; k++) {
        int b = fix_b(bcs[k], i, jb + k);
        bfix[k] = b;
        hb8[k]  = (b != 1) ? hcs[k] : 0.0f;
        oeqs[k] = (b == 1) ? 0.0f : (float)b;
    }
    *(float4*)(shb + 1 + lj)     = make_float4(hb8[0], hb8[1], hb8[2], hb8[3]);
    *(float4*)(shb + 1 + lj + 4) = make_float4(hb8[4], hb8[5], hb8[6], hb8[7]);
    *(float4*)(out_hb + base)     = make_float4(hb8[0], hb8[1], hb8[2], hb8[3]);
    *(float4*)(out_hb + base + 4) = make_float4(hb8[4], hb8[5], hb8[6], hb8[7]);
    *(float4*)(out_eq + base)     = make_float4(oeqs[0], oeqs[1], oeqs[2], oeqs[3]);
    *(float4*)(out_eq + base + 4) = make_float4(oeqs[4], oeqs[5], oeqs[6], oeqs[7]);
    __syncthreads();

    float acc[7] = {0.f,0.f,0.f,0.f,0.f,0.f,0.f};
    #pragma unroll
    for (int k = 0; k < 8; k++) {
        int j = jb + k;
        int b = bfix[k];
        float hl = (k == 0) ? shb[lj]     : hb8[k - 1];
        float hr = (k == 7) ? shb[lj + 9] : hb8[k + 1];
        float dx = (j == 0 || j == W_ - 1) ? 0.0f : 0.5f * (hr - hl);
        float hbu = (fix_b(bus[k], im, j) != 1) ? hus[k] : 0.0f;
        float hbd = (fix_b(bds[k], ip, j) != 1) ? hds[k] : 0.0f;
        float dy = 0.5f * (hbd - hbu);                  // auto-0 at i=0/H-1

        float ad = his[k] - 0.001f * (us[k] * dx + vs[k] * dy);

        float t  = hb8[k] + 273.15f;
        float t2 = t * t, t3 = t2 * t;
        float cp_a = (28.11f + 0.001967f * t + 4.802e-6f * t2 - 1.966e-9f * t3)
                     * (1000.0f / 28.97f);
        float cp_v = (32.24f + 0.001923f * t + 1.055e-5f * t2 - 3.595e-9f * t3)
                     * (1000.0f / 18.015f);
        float P_v = expf(23.2f - 3816.4f / (t - 46.1f));
        float x_v = 0.62198f * P_v / (101325.0f - P_v);
        float q = 300.0f / (cp_a + cp_v * 0.00725f) * (x_v - 0.00725f);

        float f = (i == 0 || i == H_ - 1) ? 0.0f
                  : fabsf((float)gs[k] - 1.0f) * F_FACT;

        float a_e, c_e;
        if (b == 1) {
            a_e = -f; c_e = 0.0f;
        } else {
            float cx = (b == 4 || b == 9 || b == 10) ? 1.0f
                     : ((b == 6 || b == 8 || b == 11) ? -1.0f : 0.0f);
            float cy = (b == 7 || b == 8 || b == 9) ? 1.0f
                     : ((b == 5 || b == 10 || b == 11) ? -1.0f : 0.0f);
            float extra0 = (b >= 4) ? (FLUXF * (cx * dx + cy * dy) + WC0VF) : 0.0f;
            a_e = ad + extra0 - f;
            c_e = (b >= 4) ? (-0.001f * q) : 0.0f;
        }
        acc[1] += a_e * a_e;
        acc[2] += a_e * c_e;
        acc[3] += c_e * c_e;

        float wm  = (b > 3) ? 1.0f : 0.0f;
        float wcb = wm * wss[k];
        float aw  = WC0VF * wm - wcb;
        acc[0] += wcb;
        acc[4] += aw * aw;
        acc[5] += aw * q;
        acc[6] += q * q;
    }

    #pragma unroll
    for (int off = 32; off > 0; off >>= 1) {
        #pragma unroll
        for (int s = 0; s < 7; s++) acc[s] += __shfl_down(acc[s], off, 64);
    }
    __shared__ float red[2][7];
    int lane = threadIdx.x & 63, wid = threadIdx.x >> 6;
    if (lane == 0) {
        #pragma unroll
        for (int s = 0; s < 7; s++) red[wid][s] = acc[s];
    }
    __syncthreads();
    if (threadIdx.x == 0) {
        #pragma unroll
        for (int s = 0; s < 7; s++)
            ws[s * NB_ + blockIdx.x] = red[0][s] + red[1][s];
    }
}

// Reduce NB_ partials per moment (2x float4 per thread), finish quadratics.
__global__ __launch_bounds__(256)
void k_final(const float* __restrict__ ws, float* __restrict__ out) {
    __shared__ float sred[7][4];
    int tid = threadIdx.x;
    #pragma unroll
    for (int s = 0; s < 7; s++) {
        float4 x = *(const float4*)(ws + s * NB_ + (tid << 3));
        float4 y = *(const float4*)(ws + s * NB_ + (tid << 3) + 4);
        float a = (x.x + x.y + x.z + x.w) + (y.x + y.y + y.z + y.w);
        #pragma unroll
        for (int off = 32; off > 0; off >>= 1) a += __shfl_down(a, off, 64);
        if ((tid & 63) == 0) sred[s][tid >> 6] = a;
    }
    __syncthreads();
    if (tid == 0) {
        float S[7];
        #pragma unroll
        for (int s = 0; s < 7; s++)
            S[s] = sred[s][0] + sred[s][1] + sred[s][2] + sred[s][3];
        float mean_wc = S[0] * (1.0f / (float)HW_);
        float p = POROUS_K * sqrtf(mean_wc / WC0VF);
        float energy = S[1] + 2.0f * p * S[2] + p * p * S[3];
        float wcl    = S[4] - 2.0f * p * S[5] + p * p * S[6];
        out[0] = (energy + wcl) * (1.0f / (float)HW_);
    }
}

extern "C" void kernel_launch(void* const* d_in, const int* in_sizes, int n_in,
                              void* d_out, int out_size, void* d_ws, size_t ws_size,
                              hipStream_t stream) {
    const int*   layout   = (const int*)d_in[0];
    const float* heat_ini = (const float*)d_in[1];
    const float* wc       = (const float*)d_in[2];
    const float* heat     = (const float*)d_in[3];
    const float* flow     = (const float*)d_in[4];
    float* out = (float*)d_out;    // [loss(1), heat_bc(HW), eq_mask(HW)]
    float* ws  = (float*)d_ws;     // 7 * NB_ block partials (SoA)

    float* out_hb = out + 1;
    float* out_eq = out + 1 + HW_;

    k_main<<<NB_, TPB_, 0, stream>>>(layout, heat_ini, wc, heat, flow,
                                     out_hb, out_eq, ws);
    k_final<<<1, 256, 0, stream>>>(ws, out);
}